// Round 19
// baseline (179.711 us; speedup 1.0000x reference)
//
#include <hip/hip_runtime.h>
#include <cstdint>
#include <cmath>

#define B_ 8
#define S_ 1024
#define D_ 768
#define H_ 12
#define HD_ 64

typedef __bf16 bf16;
typedef __attribute__((ext_vector_type(8))) __bf16 bf16x8;
typedef __attribute__((ext_vector_type(4))) float floatx4;

typedef const __attribute__((address_space(1))) unsigned int* gas_ptr;
typedef __attribute__((address_space(3))) unsigned int* las_ptr;

// async global->LDS, 16B per lane. LDS dest must be wave-uniform base + lane*16.
__device__ __forceinline__ void async_ld16(const void* g, void* l) {
    gas_ptr gp = (gas_ptr)(uintptr_t)g;
    las_ptr lp = (las_ptr)(unsigned)(uintptr_t)l;
    __builtin_amdgcn_global_load_lds(gp, lp, 16, 0, 0);
}

// XCD-chunked swizzle (T1): physical XCD = linear_wgid % 8. Each XCD gets a
// contiguous m-chunk so A-panels are HBM-missed once then L2-hit. ny % 8 == 0.
__device__ __forceinline__ void xcd_swizzle(int& bx, int& by) {
    const int nx = gridDim.x, ny = gridDim.y;
    const int lin = blockIdx.y * nx + blockIdx.x;
    const int xcd = lin & 7;
    const int loc = lin >> 3;
    by = xcd * (ny >> 3) + loc / nx;
    bx = loc % nx;
}

// ---- T2 bank-conflict swizzle (R14, verified: SQ_LDS_BANK_CONFLICT 2.65M -> 0).
// Pre-swizzle the GLOBAL source 16B-chunk index kp ^= (row>>1)&3 (gload_lds dest
// stays linear, rule 21); reads apply the same XOR. Involution.

// stage one [128][32] A slice + [128][32] B slice: 4 async_ld16 per thread.
__device__ __forceinline__ void stage32(const bf16* __restrict__ A,
                                        const bf16* __restrict__ Bt,
                                        long m0, long n0, long K, int kb,
                                        bf16* Asb, bf16* Bsb, int tid) {
#pragma unroll
    for (int r = 0; r < 2; r++) {
        const int idx = r * 256 + tid;
        const int rr  = idx >> 2;
        const int ks  = ((idx & 3) ^ ((idx >> 3) & 3)) * 8;   // T2 pre-swizzled source
        async_ld16(A  + (m0 + rr) * K + kb + ks, (char*)Asb + idx * 16);
        async_ld16(Bt + (n0 + rr) * K + kb + ks, (char*)Bsb + idx * 16);
    }
}

// ---------------- tiled transpose-convert body: in[K][N] f32 -> out[N][K] bf16
__device__ __forceinline__ void transpose_dev(const float* __restrict__ in,
                                              bf16* __restrict__ out,
                                              int N, int K, int n0, int k0,
                                              bf16 (*tile)[66], int tid) {
#pragma unroll
    for (int r = 0; r < 4; r++) {
        int idx = r * 256 + tid;
        int row = idx >> 4;
        int c0  = (idx & 15) * 4;
        float4 v = *(const float4*)(in + (size_t)(k0 + row) * N + n0 + c0);
        tile[c0 + 0][row] = (bf16)v.x;
        tile[c0 + 1][row] = (bf16)v.y;
        tile[c0 + 2][row] = (bf16)v.z;
        tile[c0 + 3][row] = (bf16)v.w;
    }
    __syncthreads();
#pragma unroll
    for (int r = 0; r < 2; r++) {
        int idx = r * 256 + tid;
        int orow = idx >> 3;
        int kk   = (idx & 7) * 8;
        union { bf16x8 v; bf16 e[8]; } u;
#pragma unroll
        for (int j = 0; j < 8; j++) u.e[j] = tile[orow][kk + j];
        *(bf16x8*)(out + (size_t)(n0 + orow) * K + k0 + kk) = u.v;
    }
}

// ---------------- fused prep: x f32->bf16 (blocks 0..6143), w_qkv^T (6144..6575),
// w_proj^T (6576..6719)
__global__ __launch_bounds__(256) void prep_all(
    const float* __restrict__ x, const float* __restrict__ w_qkv,
    const float* __restrict__ w_proj,
    bf16* __restrict__ xb, bf16* __restrict__ wqkvt, bf16* __restrict__ wprojt)
{
    __shared__ bf16 tile[64][66];
    const int blk = blockIdx.x, tid = threadIdx.x;
    if (blk < 6144) {
        int i = (blk * 256 + tid) * 4;
        float4 v = *(const float4*)(x + i);
        xb[i]     = (bf16)v.x;
        xb[i + 1] = (bf16)v.y;
        xb[i + 2] = (bf16)v.z;
        xb[i + 3] = (bf16)v.w;
    } else if (blk < 6576) {
        int t = blk - 6144;
        transpose_dev(w_qkv, wqkvt, 2304, 768, (t % 36) * 64, (t / 36) * 64, tile, tid);
    } else {
        int t = blk - 6576;
        transpose_dev(w_proj, wprojt, 768, 768, (t % 12) * 64, (t / 12) * 64, tile, tid);
    }
}

// ---------------- QKV GEMM v14: 128x128 tile, 2-buffer counted vmcnt at 32KB LDS
// (R19). The untested occupancy cell: counted-vmcnt was only ever run at >=48KB
// (1 blk/CU, zero cross-block overlap); 2 blk/CU only with serial/drain0
// schedules. 32KB -> 2 co-resident blocks: one block's vmcnt/barrier/ds_read
// stalls overlap the other's MFMA. Grid (18,64)=1152 = 4.5 blk/CU (small tail vs
// fat tile's 2.25 rounds at 1/CU). Loop = gemm_bt's verified structure; Q/K
// epilogue = R3-R7-verified 128² code; direct-vt V epilogue re-derived for
// i in [0,4): sbase&31 = 4g (wm in {0,64}), u = 4g+e+16(i&1),
// koff = (base5+(i>>1))*32 + 8g + 4(i&1).
__global__ __launch_bounds__(256, 2) void gemm_qkv(
    const bf16* __restrict__ A, const bf16* __restrict__ Bt,
    const float* __restrict__ bias,
    bf16* __restrict__ qpack, bf16* __restrict__ kpack, bf16* __restrict__ vt)
{
    __shared__ __align__(16) bf16 As[2][128 * 32];
    __shared__ __align__(16) bf16 Bs[2][128 * 32];
    const int N = 2304, K = 768;
    const int NKT = 24;

    const int tid  = threadIdx.x;
    const int lane = tid & 63;
    const int w    = tid >> 6;
    const int wm   = (w >> 1) * 64;
    const int wn   = (w & 1) * 64;
    int bx, by;
    xcd_swizzle(bx, by);
    const long m0  = (long)by * 128;
    const long n0  = (long)bx * 128;
    const int c    = lane & 15;
    const int g    = lane >> 4;
    const int gsw  = (g ^ ((c >> 1) & 3)) * 8;   // T2 read-side swizzled k-chunk

    const floatx4 fzero = {0.f, 0.f, 0.f, 0.f};
    floatx4 acc[4][4];
#pragma unroll
    for (int i = 0; i < 4; i++)
#pragma unroll
        for (int j = 0; j < 4; j++) acc[i][j] = fzero;

    stage32(A, Bt, m0, n0, K, 0, As[0], Bs[0], tid);

    for (int kt = 0; kt < NKT; kt++) {
        const int cur = kt & 1;
        if (kt + 1 < NKT) {
            stage32(A, Bt, m0, n0, K, (kt + 1) * 32, As[cur ^ 1], Bs[cur ^ 1], tid);
            asm volatile("s_waitcnt vmcnt(4)" ::: "memory");   // tile kt landed; kt+1 flies
        } else {
            asm volatile("s_waitcnt vmcnt(0)" ::: "memory");
        }
        __builtin_amdgcn_s_barrier();      // ALL waves' tile-kt chunks now in LDS

        bf16x8 af[4], bfr[4];
#pragma unroll
        for (int i = 0; i < 4; i++) {
            af[i]  = *(const bf16x8*)(As[cur] + (wm + i * 16 + c) * 32 + gsw);
            bfr[i] = *(const bf16x8*)(Bs[cur] + (wn + i * 16 + c) * 32 + gsw);
        }
#pragma unroll
        for (int i = 0; i < 4; i++)
#pragma unroll
            for (int j = 0; j < 4; j++)
                acc[i][j] = __builtin_amdgcn_mfma_f32_16x16x32_bf16(af[i], bfr[j], acc[i][j], 0, 0, 0);

        __builtin_amdgcn_s_barrier();      // all reads done -> safe overwrite next iter
    }

    // epilogue: wave-uniform head = (n0+wn)/64; lane c owns d' = 4c..4c+3 (b64 store)
    const int head = (int)((n0 + wn) >> 6);       // 0..35
    const int rm   = wm + g * 4;
    float bv[4];
#pragma unroll
    for (int j = 0; j < 4; j++) bv[j] = bias[(int)n0 + wn + c + 16 * j];
    const int bb    = (int)(m0 >> 10);
    const int sbase = ((int)m0 & 1023) + rm;

    if (head < 24) {
        const float sc = (head < 12) ? 0.125f : 1.0f;
        bf16* dst = ((head < 12) ? qpack : kpack)
                  + (((size_t)((bb * H_ + (head < 12 ? head : head - 12)) * 1024 + sbase)) << 6)
                  + 4 * c;
#pragma unroll
        for (int i = 0; i < 4; i++)
#pragma unroll
            for (int e = 0; e < 4; e++) {
                union { bf16 h4[4]; uint64_t u; } pk;
#pragma unroll
                for (int j = 0; j < 4; j++) pk.h4[j] = (bf16)((acc[i][j][e] + bv[j]) * sc);
                *(uint64_t*)(dst + (size_t)(i * 16 + e) * 64) = pk.u;
            }
    } else {
        // direct-vt V epilogue (R17 algebra, i range 4): row dt = c+16j;
        // koff = (base5 + (i>>1))*32 + 8g + 4(i&1); 8B store per (i,j)
        const int hv    = head - 24;
        const int base5 = (((int)m0 & 1023) + wm) >> 5;
        bf16* vrow0 = vt + ((size_t)(bb * H_ + hv) * 64 + c) * 1024;
#pragma unroll
        for (int i = 0; i < 4; i++) {
            const int koff = (base5 + (i >> 1)) * 32 + 8 * g + 4 * (i & 1);
#pragma unroll
            for (int j = 0; j < 4; j++) {
                union { bf16 h4[4]; uint64_t u; } pk;
#pragma unroll
                for (int e = 0; e < 4; e++) pk.h4[e] = (bf16)(acc[i][j][e] + bv[j]);
                *(uint64_t*)(vrow0 + (size_t)(16 * j) * 1024 + koff) = pk.u;
            }
        }
    }
}

// ---------------- generic GEMM (proj) v11 (R14): 128x128, 2-buffer counted, T2.
// Requires gridDim.y % 8 == 0.
__global__ __launch_bounds__(256, 2) void gemm_bt(
    const bf16* __restrict__ A, const bf16* __restrict__ Bt,
    const float* __restrict__ bias, float* __restrict__ C,
    int M, int N, int K)
{
    __shared__ __align__(16) bf16 As[2][128 * 32];
    __shared__ __align__(16) bf16 Bs[2][128 * 32];

    const int tid  = threadIdx.x;
    const int lane = tid & 63;
    const int w    = tid >> 6;
    const int wm   = (w >> 1) * 64;
    const int wn   = (w & 1) * 64;
    int bx, by;
    xcd_swizzle(bx, by);
    const long m0  = (long)by * 128;
    const long n0  = (long)bx * 128;
    const int c    = lane & 15;
    const int g    = lane >> 4;
    const int gsw  = (g ^ ((c >> 1) & 3)) * 8;   // T2 read-side swizzled k-chunk
    const int NKT  = K / 32;

    const floatx4 fzero = {0.f, 0.f, 0.f, 0.f};
    floatx4 acc[4][4];
#pragma unroll
    for (int i = 0; i < 4; i++)
#pragma unroll
        for (int j = 0; j < 4; j++) acc[i][j] = fzero;

    stage32(A, Bt, m0, n0, K, 0, As[0], Bs[0], tid);

    for (int kt = 0; kt < NKT; kt++) {
        const int cur = kt & 1;
        if (kt + 1 < NKT) {
            stage32(A, Bt, m0, n0, K, (kt + 1) * 32, As[cur ^ 1], Bs[cur ^ 1], tid);
            asm volatile("s_waitcnt vmcnt(4)" ::: "memory");
        } else {
            asm volatile("s_waitcnt vmcnt(0)" ::: "memory");
        }
        __builtin_amdgcn_s_barrier();

        bf16x8 af[4], bfr[4];
#pragma unroll
        for (int i = 0; i < 4; i++) {
            af[i]  = *(const bf16x8*)(As[cur] + (wm + i * 16 + c) * 32 + gsw);
            bfr[i] = *(const bf16x8*)(Bs[cur] + (wn + i * 16 + c) * 32 + gsw);
        }
#pragma unroll
        for (int i = 0; i < 4; i++)
#pragma unroll
            for (int j = 0; j < 4; j++)
                acc[i][j] = __builtin_amdgcn_mfma_f32_16x16x32_bf16(af[i], bfr[j], acc[i][j], 0, 0, 0);

        __builtin_amdgcn_s_barrier();
    }

    const int cn = wn + c;
    const int rm = wm + g * 4;
#pragma unroll
    for (int j = 0; j < 4; j++) {
        const long gn = n0 + cn + j * 16;
        const float bv = bias[gn];
#pragma unroll
        for (int i = 0; i < 4; i++) {
            const long gm = m0 + rm + i * 16;
#pragma unroll
            for (int e = 0; e < 4; e++)
                C[(gm + e) * (long)N + gn] = acc[i][j][e] + bv;
        }
    }
}

// one 32-key K/V stage for attn, T2 pre-swizzled source (R14, conflict-free).
__device__ __forceinline__ void attn_stage(const bf16* __restrict__ kpb,
                                           const bf16* __restrict__ vtb,
                                           int kg, bf16* Kb, bf16* Vb, int tid) {
    const int dsw = (tid & 3) ^ ((tid >> 3) & 3);
    const int dc = tid >> 7, key = (tid >> 2) & 31;
    async_ld16(kpb + (size_t)(kg + key) * 64 + dc * 32 + dsw * 8, (char*)Kb + tid * 16);
    const int d = tid >> 2;
    async_ld16(vtb + (size_t)d * 1024 + kg + dsw * 8, (char*)Vb + tid * 16);
}

// ---------------- fused attention v7 (R14/R17, best measured — R18's 64-q/wave
// variant regressed, reverted): 4 waves share ONE K/V stage, 4-buffer distance-2
// counted vmcnt, T2 swizzle. 768 blocks x 256 thr.
__global__ __launch_bounds__(256, 3) void attn_fused(
    const bf16* __restrict__ qpack, const bf16* __restrict__ kpack,
    const bf16* __restrict__ vt, bf16* __restrict__ outp)
{
    __shared__ __align__(16) bf16 Ks[4][2048];   // [buf][dc][key][32elem]
    __shared__ __align__(16) bf16 Vs[4][2048];   // [buf][d][32key]

    const int tid  = threadIdx.x;
    const int lane = tid & 63;
    const int w    = tid >> 6;        // 4 waves
    const int g    = lane >> 4;
    const int c    = lane & 15;
    const int gsw  = (g ^ ((c >> 1) & 3)) * 8;   // T2 read-side swizzled k-chunk

    const int id = blockIdx.x;
    const int bh = id % 96;           // same-(b,h) blocks share id mod 8 -> same XCD
    const int qt = id / 96;           // 0..7
    const int h  = bh >> 3;
    const int b  = bh & 7;
    const int q0 = qt * 128 + w * 32; // wave covers 32 q rows
    const bf16* qpb = qpack + ((size_t)(b * H_ + h) * 1024) * 64;
    const bf16* kpb = kpack + ((size_t)(b * H_ + h) * 1024) * 64;
    const bf16* vtb = vt    + ((size_t)(b * H_ + h) * 64) * 1024;

    // Q as B-operand: lane holds Q[q = q0+qb*16+c][pos = g*8+j]; loop-invariant
    bf16x8 qf[2][2];
#pragma unroll
    for (int qb = 0; qb < 2; qb++)
#pragma unroll
        for (int dc = 0; dc < 2; dc++)
            qf[qb][dc] = *(const bf16x8*)(qpb + (size_t)(q0 + qb * 16 + c) * 64 + dc * 32 + g * 8);

    union { uint32_t u[4]; bf16x8 v; } onesu;
    onesu.u[0] = onesu.u[1] = onesu.u[2] = onesu.u[3] = 0x3F803F80u;  // bf16 1.0 x8
    const bf16x8 onesf = onesu.v;

    const floatx4 fzero = {0.f, 0.f, 0.f, 0.f};
    floatx4 oacc[2][4];               // [qb][db]: Oᵀ, col=q, row=d (db*16+4g+e)
    floatx4 lacc[2];                  // [qb]: every entry = l[q=c]
#pragma unroll
    for (int qb = 0; qb < 2; qb++) {
        lacc[qb] = fzero;
#pragma unroll
        for (int db = 0; db < 4; db++) oacc[qb][db] = fzero;
    }

    // prologue: tiles 0,1 in flight (4 outstanding loads per wave)
    attn_stage(kpb, vtb, 0,  Ks[0], Vs[0], tid);
    attn_stage(kpb, vtb, 32, Ks[1], Vs[1], tid);

    for (int kt = 0; kt < 32; kt++) {       // 32-key groups
        const int cb = kt & 3;
        if (kt + 2 < 32) {
            attn_stage(kpb, vtb, (kt + 2) * 32, Ks[(kt + 2) & 3], Vs[(kt + 2) & 3], tid);
            asm volatile("s_waitcnt vmcnt(4)" ::: "memory");   // tile kt done; kt+1,kt+2 fly
        } else if (kt + 1 < 32) {
            asm volatile("s_waitcnt vmcnt(2)" ::: "memory");
        } else {
            asm volatile("s_waitcnt vmcnt(0)" ::: "memory");
        }
        __builtin_amdgcn_s_barrier();

        // K as A-operand: lane holds K[key = kb*16+c][pos = dc*32+g*8+j]
        bf16x8 kf[2][2];
#pragma unroll
        for (int kb = 0; kb < 2; kb++)
#pragma unroll
            for (int dc = 0; dc < 2; dc++)
                kf[kb][dc] = *(const bf16x8*)(Ks[cb] + (dc * 32 + kb * 16 + c) * 32 + gsw);

        // Vᵀ as A-operand: lane holds Vᵀ[d = db*16+c][key' = g*8+j]
        bf16x8 vf[4];
#pragma unroll
        for (int db = 0; db < 4; db++)
            vf[db] = *(const bf16x8*)(Vs[cb] + (db * 16 + c) * 32 + gsw);

#pragma unroll
        for (int qb = 0; qb < 2; qb++) {
            // Sᵀ for 32 keys x 16 q
            floatx4 s0 = fzero, s1 = fzero;
#pragma unroll
            for (int dc = 0; dc < 2; dc++) {
                s0 = __builtin_amdgcn_mfma_f32_16x16x32_bf16(kf[0][dc], qf[qb][dc], s0, 0, 0, 0);
                s1 = __builtin_amdgcn_mfma_f32_16x16x32_bf16(kf[1][dc], qf[qb][dc], s1, 0, 0, 0);
            }
            // P = exp(Sᵀ): lane's 8 values are exactly the PV B-operand slots
            union { bf16 e[8]; bf16x8 v; } pa;
#pragma unroll
            for (int e4 = 0; e4 < 4; e4++) {
                pa.e[e4]     = (bf16)__expf(s0[e4]);
                pa.e[e4 + 4] = (bf16)__expf(s1[e4]);
            }
            // Oᵀ += Vᵀ·Pᵀ ; l += 1·Pᵀ
            lacc[qb] = __builtin_amdgcn_mfma_f32_16x16x32_bf16(onesf, pa.v, lacc[qb], 0, 0, 0);
#pragma unroll
            for (int db = 0; db < 4; db++)
                oacc[qb][db] = __builtin_amdgcn_mfma_f32_16x16x32_bf16(vf[db], pa.v, oacc[qb][db], 0, 0, 0);
        }
    }

    // epilogue: lane holds q = q0+qb*16+c, d = db*16+4g+e; pack e-pairs -> b32 stores
#pragma unroll
    for (int qb = 0; qb < 2; qb++) {
        const float linv = 1.0f / lacc[qb][0];
        bf16* orow = outp + ((size_t)b * S_ + q0 + qb * 16 + c) * D_ + h * 64;
#pragma unroll
        for (int db = 0; db < 4; db++)
#pragma unroll
            for (int f = 0; f < 2; f++) {
                union { bf16 hh[2]; uint32_t u; } pk_;
                pk_.hh[0] = (bf16)(oacc[qb][db][2 * f]     * linv);
                pk_.hh[1] = (bf16)(oacc[qb][db][2 * f + 1] * linv);
                *(uint32_t*)(orow + db * 16 + 4 * g + 2 * f) = pk_.u;
            }
    }
}

extern "C" void kernel_launch(void* const* d_in, const int* in_sizes, int n_in,
                              void* d_out, int out_size, void* d_ws, size_t ws_size,
                              hipStream_t stream) {
    const float* x      = (const float*)d_in[0];
    const float* w_qkv  = (const float*)d_in[1];
    const float* b_qkv  = (const float*)d_in[2];
    const float* w_proj = (const float*)d_in[3];
    const float* b_proj = (const float*)d_in[4];
    float* out = (float*)d_out;

    bf16* xb     = (bf16*)d_ws;                       // [8192][768]
    bf16* wqkvt  = xb     + (size_t)8192 * 768;       // [2304][768]
    bf16* wprojt = wqkvt  + (size_t)2304 * 768;       // [768][768]
    bf16* qpack  = wprojt + (size_t)768 * 768;        // [8][12][1024][64] d'-order
    bf16* kpack  = qpack  + (size_t)96 * 1024 * 64;   // [8][12][1024][64] d'-order
    bf16* vt     = kpack  + (size_t)96 * 1024 * 64;   // [8][12][64][1024] true-d, perm keys
    bf16* attnb  = xb;                                // alias (xb dead after QKV GEMM)

    prep_all<<<6720, 256, 0, stream>>>(x, w_qkv, w_proj, xb, wqkvt, wprojt);
    gemm_qkv<<<dim3(18, 64), 256, 0, stream>>>(xb, wqkvt, b_qkv, qpack, kpack, vt);
    attn_fused<<<768, 256, 0, stream>>>(qpack, kpack, vt, attnb);
    gemm_bt<<<dim3(6, 64), 256, 0, stream>>>(attnb, wprojt, b_proj, out, 8192, 768, 768);
}

// Round 20
// 174.775 us; speedup vs baseline: 1.0282x; 1.0282x over previous
//
#include <hip/hip_runtime.h>
#include <cstdint>
#include <cmath>

#define B_ 8
#define S_ 1024
#define D_ 768
#define H_ 12
#define HD_ 64

typedef __bf16 bf16;
typedef __attribute__((ext_vector_type(8))) __bf16 bf16x8;
typedef __attribute__((ext_vector_type(4))) float floatx4;

typedef const __attribute__((address_space(1))) unsigned int* gas_ptr;
typedef __attribute__((address_space(3))) unsigned int* las_ptr;

// async global->LDS, 16B per lane. LDS dest must be wave-uniform base + lane*16.
__device__ __forceinline__ void async_ld16(const void* g, void* l) {
    gas_ptr gp = (gas_ptr)(uintptr_t)g;
    las_ptr lp = (las_ptr)(unsigned)(uintptr_t)l;
    __builtin_amdgcn_global_load_lds(gp, lp, 16, 0, 0);
}

// XCD-chunked swizzle (T1): physical XCD = linear_wgid % 8. Each XCD gets a
// contiguous m-chunk so A-panels are HBM-missed once then L2-hit. ny % 8 == 0.
__device__ __forceinline__ void xcd_swizzle(int& bx, int& by) {
    const int nx = gridDim.x, ny = gridDim.y;
    const int lin = blockIdx.y * nx + blockIdx.x;
    const int xcd = lin & 7;
    const int loc = lin >> 3;
    by = xcd * (ny >> 3) + loc / nx;
    bx = loc % nx;
}

// ---- T2 bank-conflict swizzle (R14, verified: SQ_LDS_BANK_CONFLICT 2.65M -> 0).
// Pre-swizzle the GLOBAL source 16B-chunk index kp ^= (row>>1)&3 (gload_lds dest
// stays linear, rule 21); reads apply the same XOR. Involution.

// stage A[256 rows][32] (16KB) + B[128 rows][32] (8KB): 6 async_ld16 per thread.
__device__ __forceinline__ void stage_ab(const bf16* __restrict__ A,
                                         const bf16* __restrict__ Bt,
                                         long m0, long n0, long K, int kb,
                                         bf16* Asb, bf16* Bsb, int tid) {
#pragma unroll
    for (int r = 0; r < 4; r++) {
        const int idx = r * 256 + tid;
        const int ks  = ((idx & 3) ^ ((idx >> 3) & 3)) * 8;   // T2 pre-swizzled source
        async_ld16(A + (m0 + (idx >> 2)) * K + kb + ks, (char*)Asb + idx * 16);
    }
#pragma unroll
    for (int r = 0; r < 2; r++) {
        const int idx = r * 256 + tid;
        const int ks  = ((idx & 3) ^ ((idx >> 3) & 3)) * 8;
        async_ld16(Bt + (n0 + (idx >> 2)) * K + kb + ks, (char*)Bsb + idx * 16);
    }
}

// stage one [128][32] A slice + [128][32] B slice: 4 async_ld16 per thread.
__device__ __forceinline__ void stage32(const bf16* __restrict__ A,
                                        const bf16* __restrict__ Bt,
                                        long m0, long n0, long K, int kb,
                                        bf16* Asb, bf16* Bsb, int tid) {
#pragma unroll
    for (int r = 0; r < 2; r++) {
        const int idx = r * 256 + tid;
        const int rr  = idx >> 2;
        const int ks  = ((idx & 3) ^ ((idx >> 3) & 3)) * 8;   // T2 pre-swizzled source
        async_ld16(A  + (m0 + rr) * K + kb + ks, (char*)Asb + idx * 16);
        async_ld16(Bt + (n0 + rr) * K + kb + ks, (char*)Bsb + idx * 16);
    }
}

// ---------------- tiled transpose-convert body: in[K][N] f32 -> out[N][K] bf16
__device__ __forceinline__ void transpose_dev(const float* __restrict__ in,
                                              bf16* __restrict__ out,
                                              int N, int K, int n0, int k0,
                                              bf16 (*tile)[66], int tid) {
#pragma unroll
    for (int r = 0; r < 4; r++) {
        int idx = r * 256 + tid;
        int row = idx >> 4;
        int c0  = (idx & 15) * 4;
        float4 v = *(const float4*)(in + (size_t)(k0 + row) * N + n0 + c0);
        tile[c0 + 0][row] = (bf16)v.x;
        tile[c0 + 1][row] = (bf16)v.y;
        tile[c0 + 2][row] = (bf16)v.z;
        tile[c0 + 3][row] = (bf16)v.w;
    }
    __syncthreads();
#pragma unroll
    for (int r = 0; r < 2; r++) {
        int idx = r * 256 + tid;
        int orow = idx >> 3;
        int kk   = (idx & 7) * 8;
        union { bf16x8 v; bf16 e[8]; } u;
#pragma unroll
        for (int j = 0; j < 8; j++) u.e[j] = tile[orow][kk + j];
        *(bf16x8*)(out + (size_t)(n0 + orow) * K + k0 + kk) = u.v;
    }
}

// ---------------- fused prep: x f32->bf16 (blocks 0..6143), w_qkv^T (6144..6575),
// w_proj^T (6576..6719)
__global__ __launch_bounds__(256) void prep_all(
    const float* __restrict__ x, const float* __restrict__ w_qkv,
    const float* __restrict__ w_proj,
    bf16* __restrict__ xb, bf16* __restrict__ wqkvt, bf16* __restrict__ wprojt)
{
    __shared__ bf16 tile[64][66];
    const int blk = blockIdx.x, tid = threadIdx.x;
    if (blk < 6144) {
        int i = (blk * 256 + tid) * 4;
        float4 v = *(const float4*)(x + i);
        xb[i]     = (bf16)v.x;
        xb[i + 1] = (bf16)v.y;
        xb[i + 2] = (bf16)v.z;
        xb[i + 3] = (bf16)v.w;
    } else if (blk < 6576) {
        int t = blk - 6144;
        transpose_dev(w_qkv, wqkvt, 2304, 768, (t % 36) * 64, (t / 36) * 64, tile, tid);
    } else {
        int t = blk - 6576;
        transpose_dev(w_proj, wprojt, 768, 768, (t % 12) * 64, (t / 12) * 64, tile, tid);
    }
}

// ---------------- QKV GEMM v13 (R17, best measured 45.0us): 256-thr 256x128 fat
// tile, 2-buffer counted vmcnt, T2 swizzle, DIRECT-vt V epilogue (transpose_v
// deleted). R19 falsified the occupancy theory: 128²/32KB hit 2 blk/CU (occ 26%)
// but was SLOWER (46.5) at the same 23% MfmaUtil -> the 2-phase structure is
// pinned at ~23% regardless of occupancy/tile/locality/conflicts (m233's
// structural stall). This config is the measured optimum of the family.
__global__ __launch_bounds__(256, 2) void gemm_qkv(
    const bf16* __restrict__ A, const bf16* __restrict__ Bt,
    const float* __restrict__ bias,
    bf16* __restrict__ qpack, bf16* __restrict__ kpack, bf16* __restrict__ vt)
{
    __shared__ __align__(16) bf16 As[2][256 * 32];   // 2 x 16KB
    __shared__ __align__(16) bf16 Bs[2][128 * 32];   // 2 x 8KB
    const int N = 2304, K = 768;
    const int NKT = 24;

    const int tid  = threadIdx.x;
    const int lane = tid & 63;
    const int w    = tid >> 6;
    const int wm   = (w >> 1) * 128;   // waves: 2M x 2N
    const int wn   = (w & 1) * 64;
    int bx, by;
    xcd_swizzle(bx, by);
    const long m0  = (long)by * 256;
    const long n0  = (long)bx * 128;
    const int c    = lane & 15;
    const int g    = lane >> 4;
    const int gsw  = (g ^ ((c >> 1) & 3)) * 8;   // T2 read-side swizzled k-chunk

    const floatx4 fzero = {0.f, 0.f, 0.f, 0.f};
    floatx4 acc[8][4];
#pragma unroll
    for (int i = 0; i < 8; i++)
#pragma unroll
        for (int j = 0; j < 4; j++) acc[i][j] = fzero;

    stage_ab(A, Bt, m0, n0, K, 0, As[0], Bs[0], tid);

    for (int kt = 0; kt < NKT; kt++) {
        const int cur = kt & 1;
        if (kt + 1 < NKT) {
            stage_ab(A, Bt, m0, n0, K, (kt + 1) * 32, As[cur ^ 1], Bs[cur ^ 1], tid);
            asm volatile("s_waitcnt vmcnt(6)" ::: "memory");   // tile kt landed; kt+1 flies
        } else {
            asm volatile("s_waitcnt vmcnt(0)" ::: "memory");
        }
        __builtin_amdgcn_s_barrier();      // ALL waves' tile-kt chunks now in LDS

        bf16x8 af[8], bfr[4];
#pragma unroll
        for (int i = 0; i < 8; i++)
            af[i]  = *(const bf16x8*)(As[cur] + (wm + i * 16 + c) * 32 + gsw);
#pragma unroll
        for (int j = 0; j < 4; j++)
            bfr[j] = *(const bf16x8*)(Bs[cur] + (wn + j * 16 + c) * 32 + gsw);
#pragma unroll
        for (int i = 0; i < 8; i++)
#pragma unroll
            for (int j = 0; j < 4; j++)
                acc[i][j] = __builtin_amdgcn_mfma_f32_16x16x32_bf16(af[i], bfr[j], acc[i][j], 0, 0, 0);

        __builtin_amdgcn_s_barrier();      // all reads done -> safe overwrite next iter
    }

    // epilogue: wave-uniform head = (n0+wn)/64; lane c owns d' = 4c..4c+3 (b64 store)
    const int head = (int)((n0 + wn) >> 6);       // 0..35
    const int rm   = wm + g * 4;
    float bv[4];
#pragma unroll
    for (int j = 0; j < 4; j++) bv[j] = bias[(int)n0 + wn + c + 16 * j];
    const int bb    = (int)(m0 >> 10);
    const int sbase = ((int)m0 & 1023) + rm;      // m0 multiple of 256; block within one b

    if (head < 24) {
        const float sc = (head < 12) ? 0.125f : 1.0f;
        bf16* dst = ((head < 12) ? qpack : kpack)
                  + (((size_t)((bb * H_ + (head < 12 ? head : head - 12)) * 1024 + sbase)) << 6)
                  + 4 * c;
#pragma unroll
        for (int i = 0; i < 8; i++)
#pragma unroll
            for (int e = 0; e < 4; e++) {
                union { bf16 h4[4]; uint64_t u; } pk;
#pragma unroll
                for (int j = 0; j < 4; j++) pk.h4[j] = (bf16)((acc[i][j][e] + bv[j]) * sc);
                *(uint64_t*)(dst + (size_t)(i * 16 + e) * 64) = pk.u;
            }
    } else {
        // direct-vt V epilogue: hv = head-24; row dt = c+16j; 8B store per (i,j)
        const int hv    = head - 24;
        const int base5 = (((int)m0 & 1023) + wm) >> 5;   // 32-key group base
        bf16* vrow0 = vt + ((size_t)(bb * H_ + hv) * 64 + c) * 1024;
#pragma unroll
        for (int i = 0; i < 8; i++) {
            const int koff = (base5 + (i >> 1)) * 32 + 8 * g + 4 * (i & 1);
#pragma unroll
            for (int j = 0; j < 4; j++) {
                union { bf16 h4[4]; uint64_t u; } pk;
#pragma unroll
                for (int e = 0; e < 4; e++) pk.h4[e] = (bf16)(acc[i][j][e] + bv[j]);
                *(uint64_t*)(vrow0 + (size_t)(16 * j) * 1024 + koff) = pk.u;
            }
        }
    }
}

// ---------------- generic GEMM (proj) v11 (R14): 128x128, 2-buffer counted, T2.
// Requires gridDim.y % 8 == 0.
__global__ __launch_bounds__(256, 2) void gemm_bt(
    const bf16* __restrict__ A, const bf16* __restrict__ Bt,
    const float* __restrict__ bias, float* __restrict__ C,
    int M, int N, int K)
{
    __shared__ __align__(16) bf16 As[2][128 * 32];
    __shared__ __align__(16) bf16 Bs[2][128 * 32];

    const int tid  = threadIdx.x;
    const int lane = tid & 63;
    const int w    = tid >> 6;
    const int wm   = (w >> 1) * 64;
    const int wn   = (w & 1) * 64;
    int bx, by;
    xcd_swizzle(bx, by);
    const long m0  = (long)by * 128;
    const long n0  = (long)bx * 128;
    const int c    = lane & 15;
    const int g    = lane >> 4;
    const int gsw  = (g ^ ((c >> 1) & 3)) * 8;   // T2 read-side swizzled k-chunk
    const int NKT  = K / 32;

    const floatx4 fzero = {0.f, 0.f, 0.f, 0.f};
    floatx4 acc[4][4];
#pragma unroll
    for (int i = 0; i < 4; i++)
#pragma unroll
        for (int j = 0; j < 4; j++) acc[i][j] = fzero;

    stage32(A, Bt, m0, n0, K, 0, As[0], Bs[0], tid);

    for (int kt = 0; kt < NKT; kt++) {
        const int cur = kt & 1;
        if (kt + 1 < NKT) {
            stage32(A, Bt, m0, n0, K, (kt + 1) * 32, As[cur ^ 1], Bs[cur ^ 1], tid);
            asm volatile("s_waitcnt vmcnt(4)" ::: "memory");
        } else {
            asm volatile("s_waitcnt vmcnt(0)" ::: "memory");
        }
        __builtin_amdgcn_s_barrier();

        bf16x8 af[4], bfr[4];
#pragma unroll
        for (int i = 0; i < 4; i++) {
            af[i]  = *(const bf16x8*)(As[cur] + (wm + i * 16 + c) * 32 + gsw);
            bfr[i] = *(const bf16x8*)(Bs[cur] + (wn + i * 16 + c) * 32 + gsw);
        }
#pragma unroll
        for (int i = 0; i < 4; i++)
#pragma unroll
            for (int j = 0; j < 4; j++)
                acc[i][j] = __builtin_amdgcn_mfma_f32_16x16x32_bf16(af[i], bfr[j], acc[i][j], 0, 0, 0);

        __builtin_amdgcn_s_barrier();
    }

    const int cn = wn + c;
    const int rm = wm + g * 4;
#pragma unroll
    for (int j = 0; j < 4; j++) {
        const long gn = n0 + cn + j * 16;
        const float bv = bias[gn];
#pragma unroll
        for (int i = 0; i < 4; i++) {
            const long gm = m0 + rm + i * 16;
#pragma unroll
            for (int e = 0; e < 4; e++)
                C[(gm + e) * (long)N + gn] = acc[i][j][e] + bv;
        }
    }
}

// one 32-key K/V stage for attn, T2 pre-swizzled source (R14, conflict-free).
__device__ __forceinline__ void attn_stage(const bf16* __restrict__ kpb,
                                           const bf16* __restrict__ vtb,
                                           int kg, bf16* Kb, bf16* Vb, int tid) {
    const int dsw = (tid & 3) ^ ((tid >> 3) & 3);
    const int dc = tid >> 7, key = (tid >> 2) & 31;
    async_ld16(kpb + (size_t)(kg + key) * 64 + dc * 32 + dsw * 8, (char*)Kb + tid * 16);
    const int d = tid >> 2;
    async_ld16(vtb + (size_t)d * 1024 + kg + dsw * 8, (char*)Vb + tid * 16);
}

// ---------------- fused attention v10: v7 (R14/R17 verified) + T5 setprio ONLY.
// R15 bundled 3 changes (2-buffer, end-barrier, setprio) and regressed; the
// pipeline change was the culprit candidate. Clean A/B: setprio(1/0) around the
// MFMA+exp compute cluster, nothing else touched. m191: +4-7% on attn in exactly
// this regime (2-3 independent blocks/CU at different phases).
__global__ __launch_bounds__(256, 3) void attn_fused(
    const bf16* __restrict__ qpack, const bf16* __restrict__ kpack,
    const bf16* __restrict__ vt, bf16* __restrict__ outp)
{
    __shared__ __align__(16) bf16 Ks[4][2048];   // [buf][dc][key][32elem]
    __shared__ __align__(16) bf16 Vs[4][2048];   // [buf][d][32key]

    const int tid  = threadIdx.x;
    const int lane = tid & 63;
    const int w    = tid >> 6;        // 4 waves
    const int g    = lane >> 4;
    const int c    = lane & 15;
    const int gsw  = (g ^ ((c >> 1) & 3)) * 8;   // T2 read-side swizzled k-chunk

    const int id = blockIdx.x;
    const int bh = id % 96;           // same-(b,h) blocks share id mod 8 -> same XCD
    const int qt = id / 96;           // 0..7
    const int h  = bh >> 3;
    const int b  = bh & 7;
    const int q0 = qt * 128 + w * 32; // wave covers 32 q rows
    const bf16* qpb = qpack + ((size_t)(b * H_ + h) * 1024) * 64;
    const bf16* kpb = kpack + ((size_t)(b * H_ + h) * 1024) * 64;
    const bf16* vtb = vt    + ((size_t)(b * H_ + h) * 64) * 1024;

    // Q as B-operand: lane holds Q[q = q0+qb*16+c][pos = g*8+j]; loop-invariant
    bf16x8 qf[2][2];
#pragma unroll
    for (int qb = 0; qb < 2; qb++)
#pragma unroll
        for (int dc = 0; dc < 2; dc++)
            qf[qb][dc] = *(const bf16x8*)(qpb + (size_t)(q0 + qb * 16 + c) * 64 + dc * 32 + g * 8);

    union { uint32_t u[4]; bf16x8 v; } onesu;
    onesu.u[0] = onesu.u[1] = onesu.u[2] = onesu.u[3] = 0x3F803F80u;  // bf16 1.0 x8
    const bf16x8 onesf = onesu.v;

    const floatx4 fzero = {0.f, 0.f, 0.f, 0.f};
    floatx4 oacc[2][4];               // [qb][db]: Oᵀ, col=q, row=d (db*16+4g+e)
    floatx4 lacc[2];                  // [qb]: every entry = l[q=c]
#pragma unroll
    for (int qb = 0; qb < 2; qb++) {
        lacc[qb] = fzero;
#pragma unroll
        for (int db = 0; db < 4; db++) oacc[qb][db] = fzero;
    }

    // prologue: tiles 0,1 in flight (4 outstanding loads per wave)
    attn_stage(kpb, vtb, 0,  Ks[0], Vs[0], tid);
    attn_stage(kpb, vtb, 32, Ks[1], Vs[1], tid);

    for (int kt = 0; kt < 32; kt++) {       // 32-key groups
        const int cb = kt & 3;
        if (kt + 2 < 32) {
            attn_stage(kpb, vtb, (kt + 2) * 32, Ks[(kt + 2) & 3], Vs[(kt + 2) & 3], tid);
            asm volatile("s_waitcnt vmcnt(4)" ::: "memory");   // tile kt done; kt+1,kt+2 fly
        } else if (kt + 1 < 32) {
            asm volatile("s_waitcnt vmcnt(2)" ::: "memory");
        } else {
            asm volatile("s_waitcnt vmcnt(0)" ::: "memory");
        }
        __builtin_amdgcn_s_barrier();

        // K as A-operand: lane holds K[key = kb*16+c][pos = dc*32+g*8+j]
        bf16x8 kf[2][2];
#pragma unroll
        for (int kb = 0; kb < 2; kb++)
#pragma unroll
            for (int dc = 0; dc < 2; dc++)
                kf[kb][dc] = *(const bf16x8*)(Ks[cb] + (dc * 32 + kb * 16 + c) * 32 + gsw);

        // Vᵀ as A-operand: lane holds Vᵀ[d = db*16+c][key' = g*8+j]
        bf16x8 vf[4];
#pragma unroll
        for (int db = 0; db < 4; db++)
            vf[db] = *(const bf16x8*)(Vs[cb] + (db * 16 + c) * 32 + gsw);

        __builtin_amdgcn_s_setprio(1);
#pragma unroll
        for (int qb = 0; qb < 2; qb++) {
            // Sᵀ for 32 keys x 16 q
            floatx4 s0 = fzero, s1 = fzero;
#pragma unroll
            for (int dc = 0; dc < 2; dc++) {
                s0 = __builtin_amdgcn_mfma_f32_16x16x32_bf16(kf[0][dc], qf[qb][dc], s0, 0, 0, 0);
                s1 = __builtin_amdgcn_mfma_f32_16x16x32_bf16(kf[1][dc], qf[qb][dc], s1, 0, 0, 0);
            }
            // P = exp(Sᵀ): lane's 8 values are exactly the PV B-operand slots
            union { bf16 e[8]; bf16x8 v; } pa;
#pragma unroll
            for (int e4 = 0; e4 < 4; e4++) {
                pa.e[e4]     = (bf16)__expf(s0[e4]);
                pa.e[e4 + 4] = (bf16)__expf(s1[e4]);
            }
            // Oᵀ += Vᵀ·Pᵀ ; l += 1·Pᵀ
            lacc[qb] = __builtin_amdgcn_mfma_f32_16x16x32_bf16(onesf, pa.v, lacc[qb], 0, 0, 0);
#pragma unroll
            for (int db = 0; db < 4; db++)
                oacc[qb][db] = __builtin_amdgcn_mfma_f32_16x16x32_bf16(vf[db], pa.v, oacc[qb][db], 0, 0, 0);
        }
        __builtin_amdgcn_s_setprio(0);
    }

    // epilogue: lane holds q = q0+qb*16+c, d = db*16+4g+e; pack e-pairs -> b32 stores
#pragma unroll
    for (int qb = 0; qb < 2; qb++) {
        const float linv = 1.0f / lacc[qb][0];
        bf16* orow = outp + ((size_t)b * S_ + q0 + qb * 16 + c) * D_ + h * 64;
#pragma unroll
        for (int db = 0; db < 4; db++)
#pragma unroll
            for (int f = 0; f < 2; f++) {
                union { bf16 hh[2]; uint32_t u; } pk_;
                pk_.hh[0] = (bf16)(oacc[qb][db][2 * f]     * linv);
                pk_.hh[1] = (bf16)(oacc[qb][db][2 * f + 1] * linv);
                *(uint32_t*)(orow + db * 16 + 4 * g + 2 * f) = pk_.u;
            }
    }
}

extern "C" void kernel_launch(void* const* d_in, const int* in_sizes, int n_in,
                              void* d_out, int out_size, void* d_ws, size_t ws_size,
                              hipStream_t stream) {
    const float* x      = (const float*)d_in[0];
    const float* w_qkv  = (const float*)d_in[1];
    const float* b_qkv  = (const float*)d_in[2];
    const float* w_proj = (const float*)d_in[3];
    const float* b_proj = (const float*)d_in[4];
    float* out = (float*)d_out;

    bf16* xb     = (bf16*)d_ws;                       // [8192][768]
    bf16* wqkvt  = xb     + (size_t)8192 * 768;       // [2304][768]
    bf16* wprojt = wqkvt  + (size_t)2304 * 768;       // [768][768]
    bf16* qpack  = wprojt + (size_t)768 * 768;        // [8][12][1024][64] d'-order
    bf16* kpack  = qpack  + (size_t)96 * 1024 * 64;   // [8][12][1024][64] d'-order
    bf16* vt     = kpack  + (size_t)96 * 1024 * 64;   // [8][12][64][1024] true-d, perm keys
    bf16* attnb  = xb;                                // alias (xb dead after QKV GEMM)

    prep_all<<<6720, 256, 0, stream>>>(x, w_qkv, w_proj, xb, wqkvt, wprojt);
    gemm_qkv<<<dim3(18, 32), 256, 0, stream>>>(xb, wqkvt, b_qkv, qpack, kpack, vt);
    attn_fused<<<768, 256, 0, stream>>>(qpack, kpack, vt, attnb);
    gemm_bt<<<dim3(6, 64), 256, 0, stream>>>(attnb, wprojt, b_proj, out, 8192, 768, 768);
}

// Round 21
// 171.694 us; speedup vs baseline: 1.0467x; 1.0179x over previous
//
#include <hip/hip_runtime.h>
#include <cstdint>
#include <cmath>

#define B_ 8
#define S_ 1024
#define D_ 768
#define H_ 12
#define HD_ 64

typedef __bf16 bf16;
typedef __attribute__((ext_vector_type(8))) __bf16 bf16x8;
typedef __attribute__((ext_vector_type(4))) float floatx4;

typedef const __attribute__((address_space(1))) unsigned int* gas_ptr;
typedef __attribute__((address_space(3))) unsigned int* las_ptr;

// async global->LDS, 16B per lane. LDS dest must be wave-uniform base + lane*16.
__device__ __forceinline__ void async_ld16(const void* g, void* l) {
    gas_ptr gp = (gas_ptr)(uintptr_t)g;
    las_ptr lp = (las_ptr)(unsigned)(uintptr_t)l;
    __builtin_amdgcn_global_load_lds(gp, lp, 16, 0, 0);
}

// XCD-chunked swizzle (T1): physical XCD = linear_wgid % 8. Each XCD gets a
// contiguous m-chunk so A-panels are HBM-missed once then L2-hit. ny % 8 == 0.
// Verified R4: FETCH 67.5 -> 37.8 MB on gemm_qkv.
__device__ __forceinline__ void xcd_swizzle(int& bx, int& by) {
    const int nx = gridDim.x, ny = gridDim.y;
    const int lin = blockIdx.y * nx + blockIdx.x;
    const int xcd = lin & 7;
    const int loc = lin >> 3;
    by = xcd * (ny >> 3) + loc / nx;
    bx = loc % nx;
}

// ---- T2 bank-conflict swizzle (R14, verified: SQ_LDS_BANK_CONFLICT 2.65M -> 0).
// Pre-swizzle the GLOBAL source 16B-chunk index kp ^= (row>>1)&3 (gload_lds dest
// stays linear, rule 21); reads apply the same XOR. Involution.

// stage A[256 rows][32] (16KB) + B[128 rows][32] (8KB): 6 async_ld16 per thread.
__device__ __forceinline__ void stage_ab(const bf16* __restrict__ A,
                                         const bf16* __restrict__ Bt,
                                         long m0, long n0, long K, int kb,
                                         bf16* Asb, bf16* Bsb, int tid) {
#pragma unroll
    for (int r = 0; r < 4; r++) {
        const int idx = r * 256 + tid;
        const int ks  = ((idx & 3) ^ ((idx >> 3) & 3)) * 8;   // T2 pre-swizzled source
        async_ld16(A + (m0 + (idx >> 2)) * K + kb + ks, (char*)Asb + idx * 16);
    }
#pragma unroll
    for (int r = 0; r < 2; r++) {
        const int idx = r * 256 + tid;
        const int ks  = ((idx & 3) ^ ((idx >> 3) & 3)) * 8;
        async_ld16(Bt + (n0 + (idx >> 2)) * K + kb + ks, (char*)Bsb + idx * 16);
    }
}

// stage one [128][32] A slice + [128][32] B slice: 4 async_ld16 per thread.
__device__ __forceinline__ void stage32(const bf16* __restrict__ A,
                                        const bf16* __restrict__ Bt,
                                        long m0, long n0, long K, int kb,
                                        bf16* Asb, bf16* Bsb, int tid) {
#pragma unroll
    for (int r = 0; r < 2; r++) {
        const int idx = r * 256 + tid;
        const int rr  = idx >> 2;
        const int ks  = ((idx & 3) ^ ((idx >> 3) & 3)) * 8;   // T2 pre-swizzled source
        async_ld16(A  + (m0 + rr) * K + kb + ks, (char*)Asb + idx * 16);
        async_ld16(Bt + (n0 + rr) * K + kb + ks, (char*)Bsb + idx * 16);
    }
}

// ---------------- tiled transpose-convert body: in[K][N] f32 -> out[N][K] bf16
__device__ __forceinline__ void transpose_dev(const float* __restrict__ in,
                                              bf16* __restrict__ out,
                                              int N, int K, int n0, int k0,
                                              bf16 (*tile)[66], int tid) {
#pragma unroll
    for (int r = 0; r < 4; r++) {
        int idx = r * 256 + tid;
        int row = idx >> 4;
        int c0  = (idx & 15) * 4;
        float4 v = *(const float4*)(in + (size_t)(k0 + row) * N + n0 + c0);
        tile[c0 + 0][row] = (bf16)v.x;
        tile[c0 + 1][row] = (bf16)v.y;
        tile[c0 + 2][row] = (bf16)v.z;
        tile[c0 + 3][row] = (bf16)v.w;
    }
    __syncthreads();
#pragma unroll
    for (int r = 0; r < 2; r++) {
        int idx = r * 256 + tid;
        int orow = idx >> 3;
        int kk   = (idx & 7) * 8;
        union { bf16x8 v; bf16 e[8]; } u;
#pragma unroll
        for (int j = 0; j < 8; j++) u.e[j] = tile[orow][kk + j];
        *(bf16x8*)(out + (size_t)(n0 + orow) * K + k0 + kk) = u.v;
    }
}

// ---------------- fused prep: x f32->bf16 (blocks 0..6143), w_qkv^T (6144..6575),
// w_proj^T (6576..6719)
__global__ __launch_bounds__(256) void prep_all(
    const float* __restrict__ x, const float* __restrict__ w_qkv,
    const float* __restrict__ w_proj,
    bf16* __restrict__ xb, bf16* __restrict__ wqkvt, bf16* __restrict__ wprojt)
{
    __shared__ bf16 tile[64][66];
    const int blk = blockIdx.x, tid = threadIdx.x;
    if (blk < 6144) {
        int i = (blk * 256 + tid) * 4;
        float4 v = *(const float4*)(x + i);
        xb[i]     = (bf16)v.x;
        xb[i + 1] = (bf16)v.y;
        xb[i + 2] = (bf16)v.z;
        xb[i + 3] = (bf16)v.w;
    } else if (blk < 6576) {
        int t = blk - 6144;
        transpose_dev(w_qkv, wqkvt, 2304, 768, (t % 36) * 64, (t / 36) * 64, tile, tid);
    } else {
        int t = blk - 6576;
        transpose_dev(w_proj, wprojt, 768, 768, (t % 12) * 64, (t / 12) * 64, tile, tid);
    }
}

// ---------------- QKV GEMM v13 (R17, session-best 173.3us total): 256-thr
// 256x128 fat tile, 2-buffer counted vmcnt, T2 swizzle, DIRECT-vt V epilogue
// (transpose_v deleted; saves 25MB round-trip + a launch). Session findings:
// the 2-phase counted-vmcnt structure is pinned at ~23% MfmaUtil regardless of
// BK/occupancy/tile/locality/conflicts (m233 structural stall); this config is
// the measured optimum of the family. Next lever would be the full 8-phase port.
__global__ __launch_bounds__(256, 2) void gemm_qkv(
    const bf16* __restrict__ A, const bf16* __restrict__ Bt,
    const float* __restrict__ bias,
    bf16* __restrict__ qpack, bf16* __restrict__ kpack, bf16* __restrict__ vt)
{
    __shared__ __align__(16) bf16 As[2][256 * 32];   // 2 x 16KB
    __shared__ __align__(16) bf16 Bs[2][128 * 32];   // 2 x 8KB
    const int N = 2304, K = 768;
    const int NKT = 24;

    const int tid  = threadIdx.x;
    const int lane = tid & 63;
    const int w    = tid >> 6;
    const int wm   = (w >> 1) * 128;   // waves: 2M x 2N
    const int wn   = (w & 1) * 64;
    int bx, by;
    xcd_swizzle(bx, by);
    const long m0  = (long)by * 256;
    const long n0  = (long)bx * 128;
    const int c    = lane & 15;
    const int g    = lane >> 4;
    const int gsw  = (g ^ ((c >> 1) & 3)) * 8;   // T2 read-side swizzled k-chunk

    const floatx4 fzero = {0.f, 0.f, 0.f, 0.f};
    floatx4 acc[8][4];
#pragma unroll
    for (int i = 0; i < 8; i++)
#pragma unroll
        for (int j = 0; j < 4; j++) acc[i][j] = fzero;

    stage_ab(A, Bt, m0, n0, K, 0, As[0], Bs[0], tid);

    for (int kt = 0; kt < NKT; kt++) {
        const int cur = kt & 1;
        if (kt + 1 < NKT) {
            stage_ab(A, Bt, m0, n0, K, (kt + 1) * 32, As[cur ^ 1], Bs[cur ^ 1], tid);
            asm volatile("s_waitcnt vmcnt(6)" ::: "memory");   // tile kt landed; kt+1 flies
        } else {
            asm volatile("s_waitcnt vmcnt(0)" ::: "memory");
        }
        __builtin_amdgcn_s_barrier();      // ALL waves' tile-kt chunks now in LDS

        bf16x8 af[8], bfr[4];
#pragma unroll
        for (int i = 0; i < 8; i++)
            af[i]  = *(const bf16x8*)(As[cur] + (wm + i * 16 + c) * 32 + gsw);
#pragma unroll
        for (int j = 0; j < 4; j++)
            bfr[j] = *(const bf16x8*)(Bs[cur] + (wn + j * 16 + c) * 32 + gsw);
#pragma unroll
        for (int i = 0; i < 8; i++)
#pragma unroll
            for (int j = 0; j < 4; j++)
                acc[i][j] = __builtin_amdgcn_mfma_f32_16x16x32_bf16(af[i], bfr[j], acc[i][j], 0, 0, 0);

        __builtin_amdgcn_s_barrier();      // all reads done -> safe overwrite next iter
    }

    // epilogue: wave-uniform head = (n0+wn)/64; lane c owns d' = 4c..4c+3 (b64 store)
    const int head = (int)((n0 + wn) >> 6);       // 0..35
    const int rm   = wm + g * 4;
    float bv[4];
#pragma unroll
    for (int j = 0; j < 4; j++) bv[j] = bias[(int)n0 + wn + c + 16 * j];
    const int bb    = (int)(m0 >> 10);
    const int sbase = ((int)m0 & 1023) + rm;      // m0 multiple of 256; block within one b

    if (head < 24) {
        const float sc = (head < 12) ? 0.125f : 1.0f;
        bf16* dst = ((head < 12) ? qpack : kpack)
                  + (((size_t)((bb * H_ + (head < 12 ? head : head - 12)) * 1024 + sbase)) << 6)
                  + 4 * c;
#pragma unroll
        for (int i = 0; i < 8; i++)
#pragma unroll
            for (int e = 0; e < 4; e++) {
                union { bf16 h4[4]; uint64_t u; } pk;
#pragma unroll
                for (int j = 0; j < 4; j++) pk.h4[j] = (bf16)((acc[i][j][e] + bv[j]) * sc);
                *(uint64_t*)(dst + (size_t)(i * 16 + e) * 64) = pk.u;
            }
    } else {
        // direct-vt V epilogue: hv = head-24; row dt = c+16j; 8B store per (i,j)
        const int hv    = head - 24;
        const int base5 = (((int)m0 & 1023) + wm) >> 5;   // 32-key group base
        bf16* vrow0 = vt + ((size_t)(bb * H_ + hv) * 64 + c) * 1024;
#pragma unroll
        for (int i = 0; i < 8; i++) {
            const int koff = (base5 + (i >> 1)) * 32 + 8 * g + 4 * (i & 1);
#pragma unroll
            for (int j = 0; j < 4; j++) {
                union { bf16 h4[4]; uint64_t u; } pk;
#pragma unroll
                for (int e = 0; e < 4; e++) pk.h4[e] = (bf16)(acc[i][j][e] + bv[j]);
                *(uint64_t*)(vrow0 + (size_t)(16 * j) * 1024 + koff) = pk.u;
            }
        }
    }
}

// ---------------- generic GEMM (proj) v11 (R14): 128x128, 2-buffer counted, T2.
// Requires gridDim.y % 8 == 0.
__global__ __launch_bounds__(256, 2) void gemm_bt(
    const bf16* __restrict__ A, const bf16* __restrict__ Bt,
    const float* __restrict__ bias, float* __restrict__ C,
    int M, int N, int K)
{
    __shared__ __align__(16) bf16 As[2][128 * 32];
    __shared__ __align__(16) bf16 Bs[2][128 * 32];

    const int tid  = threadIdx.x;
    const int lane = tid & 63;
    const int w    = tid >> 6;
    const int wm   = (w >> 1) * 64;
    const int wn   = (w & 1) * 64;
    int bx, by;
    xcd_swizzle(bx, by);
    const long m0  = (long)by * 128;
    const long n0  = (long)bx * 128;
    const int c    = lane & 15;
    const int g    = lane >> 4;
    const int gsw  = (g ^ ((c >> 1) & 3)) * 8;   // T2 read-side swizzled k-chunk
    const int NKT  = K / 32;

    const floatx4 fzero = {0.f, 0.f, 0.f, 0.f};
    floatx4 acc[4][4];
#pragma unroll
    for (int i = 0; i < 4; i++)
#pragma unroll
        for (int j = 0; j < 4; j++) acc[i][j] = fzero;

    stage32(A, Bt, m0, n0, K, 0, As[0], Bs[0], tid);

    for (int kt = 0; kt < NKT; kt++) {
        const int cur = kt & 1;
        if (kt + 1 < NKT) {
            stage32(A, Bt, m0, n0, K, (kt + 1) * 32, As[cur ^ 1], Bs[cur ^ 1], tid);
            asm volatile("s_waitcnt vmcnt(4)" ::: "memory");
        } else {
            asm volatile("s_waitcnt vmcnt(0)" ::: "memory");
        }
        __builtin_amdgcn_s_barrier();

        bf16x8 af[4], bfr[4];
#pragma unroll
        for (int i = 0; i < 4; i++) {
            af[i]  = *(const bf16x8*)(As[cur] + (wm + i * 16 + c) * 32 + gsw);
            bfr[i] = *(const bf16x8*)(Bs[cur] + (wn + i * 16 + c) * 32 + gsw);
        }
#pragma unroll
        for (int i = 0; i < 4; i++)
#pragma unroll
            for (int j = 0; j < 4; j++)
                acc[i][j] = __builtin_amdgcn_mfma_f32_16x16x32_bf16(af[i], bfr[j], acc[i][j], 0, 0, 0);

        __builtin_amdgcn_s_barrier();
    }

    const int cn = wn + c;
    const int rm = wm + g * 4;
#pragma unroll
    for (int j = 0; j < 4; j++) {
        const long gn = n0 + cn + j * 16;
        const float bv = bias[gn];
#pragma unroll
        for (int i = 0; i < 4; i++) {
            const long gm = m0 + rm + i * 16;
#pragma unroll
            for (int e = 0; e < 4; e++)
                C[(gm + e) * (long)N + gn] = acc[i][j][e] + bv;
        }
    }
}

// one 32-key K/V stage for attn, T2 pre-swizzled source (R14, conflict-free).
__device__ __forceinline__ void attn_stage(const bf16* __restrict__ kpb,
                                           const bf16* __restrict__ vtb,
                                           int kg, bf16* Kb, bf16* Vb, int tid) {
    const int dsw = (tid & 3) ^ ((tid >> 3) & 3);
    const int dc = tid >> 7, key = (tid >> 2) & 31;
    async_ld16(kpb + (size_t)(kg + key) * 64 + dc * 32 + dsw * 8, (char*)Kb + tid * 16);
    const int d = tid >> 2;
    async_ld16(vtb + (size_t)d * 1024 + kg + dsw * 8, (char*)Vb + tid * 16);
}

// ---------------- fused attention v7 (R14/R17 verified best; R20's setprio was
// neutral-to-negative and is removed): 4 waves share ONE K/V stage, 4-buffer
// distance-2 counted vmcnt, T2 swizzle. 768 blocks x 256 thr.
__global__ __launch_bounds__(256, 3) void attn_fused(
    const bf16* __restrict__ qpack, const bf16* __restrict__ kpack,
    const bf16* __restrict__ vt, bf16* __restrict__ outp)
{
    __shared__ __align__(16) bf16 Ks[4][2048];   // [buf][dc][key][32elem]
    __shared__ __align__(16) bf16 Vs[4][2048];   // [buf][d][32key]

    const int tid  = threadIdx.x;
    const int lane = tid & 63;
    const int w    = tid >> 6;        // 4 waves
    const int g    = lane >> 4;
    const int c    = lane & 15;
    const int gsw  = (g ^ ((c >> 1) & 3)) * 8;   // T2 read-side swizzled k-chunk

    const int id = blockIdx.x;
    const int bh = id % 96;           // same-(b,h) blocks share id mod 8 -> same XCD
    const int qt = id / 96;           // 0..7
    const int h  = bh >> 3;
    const int b  = bh & 7;
    const int q0 = qt * 128 + w * 32; // wave covers 32 q rows
    const bf16* qpb = qpack + ((size_t)(b * H_ + h) * 1024) * 64;
    const bf16* kpb = kpack + ((size_t)(b * H_ + h) * 1024) * 64;
    const bf16* vtb = vt    + ((size_t)(b * H_ + h) * 64) * 1024;

    // Q as B-operand: lane holds Q[q = q0+qb*16+c][pos = g*8+j]; loop-invariant
    bf16x8 qf[2][2];
#pragma unroll
    for (int qb = 0; qb < 2; qb++)
#pragma unroll
        for (int dc = 0; dc < 2; dc++)
            qf[qb][dc] = *(const bf16x8*)(qpb + (size_t)(q0 + qb * 16 + c) * 64 + dc * 32 + g * 8);

    union { uint32_t u[4]; bf16x8 v; } onesu;
    onesu.u[0] = onesu.u[1] = onesu.u[2] = onesu.u[3] = 0x3F803F80u;  // bf16 1.0 x8
    const bf16x8 onesf = onesu.v;

    const floatx4 fzero = {0.f, 0.f, 0.f, 0.f};
    floatx4 oacc[2][4];               // [qb][db]: Oᵀ, col=q, row=d (db*16+4g+e)
    floatx4 lacc[2];                  // [qb]: every entry = l[q=c]
#pragma unroll
    for (int qb = 0; qb < 2; qb++) {
        lacc[qb] = fzero;
#pragma unroll
        for (int db = 0; db < 4; db++) oacc[qb][db] = fzero;
    }

    // prologue: tiles 0,1 in flight (4 outstanding loads per wave)
    attn_stage(kpb, vtb, 0,  Ks[0], Vs[0], tid);
    attn_stage(kpb, vtb, 32, Ks[1], Vs[1], tid);

    for (int kt = 0; kt < 32; kt++) {       // 32-key groups
        const int cb = kt & 3;
        if (kt + 2 < 32) {
            attn_stage(kpb, vtb, (kt + 2) * 32, Ks[(kt + 2) & 3], Vs[(kt + 2) & 3], tid);
            asm volatile("s_waitcnt vmcnt(4)" ::: "memory");   // tile kt done; kt+1,kt+2 fly
        } else if (kt + 1 < 32) {
            asm volatile("s_waitcnt vmcnt(2)" ::: "memory");
        } else {
            asm volatile("s_waitcnt vmcnt(0)" ::: "memory");
        }
        __builtin_amdgcn_s_barrier();

        // K as A-operand: lane holds K[key = kb*16+c][pos = dc*32+g*8+j]
        bf16x8 kf[2][2];
#pragma unroll
        for (int kb = 0; kb < 2; kb++)
#pragma unroll
            for (int dc = 0; dc < 2; dc++)
                kf[kb][dc] = *(const bf16x8*)(Ks[cb] + (dc * 32 + kb * 16 + c) * 32 + gsw);

        // Vᵀ as A-operand: lane holds Vᵀ[d = db*16+c][key' = g*8+j]
        bf16x8 vf[4];
#pragma unroll
        for (int db = 0; db < 4; db++)
            vf[db] = *(const bf16x8*)(Vs[cb] + (db * 16 + c) * 32 + gsw);

#pragma unroll
        for (int qb = 0; qb < 2; qb++) {
            // Sᵀ for 32 keys x 16 q
            floatx4 s0 = fzero, s1 = fzero;
#pragma unroll
            for (int dc = 0; dc < 2; dc++) {
                s0 = __builtin_amdgcn_mfma_f32_16x16x32_bf16(kf[0][dc], qf[qb][dc], s0, 0, 0, 0);
                s1 = __builtin_amdgcn_mfma_f32_16x16x32_bf16(kf[1][dc], qf[qb][dc], s1, 0, 0, 0);
            }
            // P = exp(Sᵀ): lane's 8 values are exactly the PV B-operand slots
            union { bf16 e[8]; bf16x8 v; } pa;
#pragma unroll
            for (int e4 = 0; e4 < 4; e4++) {
                pa.e[e4]     = (bf16)__expf(s0[e4]);
                pa.e[e4 + 4] = (bf16)__expf(s1[e4]);
            }
            // Oᵀ += Vᵀ·Pᵀ ; l += 1·Pᵀ
            lacc[qb] = __builtin_amdgcn_mfma_f32_16x16x32_bf16(onesf, pa.v, lacc[qb], 0, 0, 0);
#pragma unroll
            for (int db = 0; db < 4; db++)
                oacc[qb][db] = __builtin_amdgcn_mfma_f32_16x16x32_bf16(vf[db], pa.v, oacc[qb][db], 0, 0, 0);
        }
    }

    // epilogue: lane holds q = q0+qb*16+c, d = db*16+4g+e; pack e-pairs -> b32 stores
#pragma unroll
    for (int qb = 0; qb < 2; qb++) {
        const float linv = 1.0f / lacc[qb][0];
        bf16* orow = outp + ((size_t)b * S_ + q0 + qb * 16 + c) * D_ + h * 64;
#pragma unroll
        for (int db = 0; db < 4; db++)
#pragma unroll
            for (int f = 0; f < 2; f++) {
                union { bf16 hh[2]; uint32_t u; } pk_;
                pk_.hh[0] = (bf16)(oacc[qb][db][2 * f]     * linv);
                pk_.hh[1] = (bf16)(oacc[qb][db][2 * f + 1] * linv);
                *(uint32_t*)(orow + db * 16 + 4 * g + 2 * f) = pk_.u;
            }
    }
}

extern "C" void kernel_launch(void* const* d_in, const int* in_sizes, int n_in,
                              void* d_out, int out_size, void* d_ws, size_t ws_size,
                              hipStream_t stream) {
    const float* x      = (const float*)d_in[0];
    const float* w_qkv  = (const float*)d_in[1];
    const float* b_qkv  = (const float*)d_in[2];
    const float* w_proj = (const float*)d_in[3];
    const float* b_proj = (const float*)d_in[4];
    float* out = (float*)d_out;

    bf16* xb     = (bf16*)d_ws;                       // [8192][768]
    bf16* wqkvt  = xb     + (size_t)8192 * 768;       // [2304][768]
    bf16* wprojt = wqkvt  + (size_t)2304 * 768;       // [768][768]
    bf16* qpack  = wprojt + (size_t)768 * 768;        // [8][12][1024][64] d'-order
    bf16* kpack  = qpack  + (size_t)96 * 1024 * 64;   // [8][12][1024][64] d'-order
    bf16* vt     = kpack  + (size_t)96 * 1024 * 64;   // [8][12][64][1024] true-d, perm keys
    bf16* attnb  = xb;                                // alias (xb dead after QKV GEMM)

    prep_all<<<6720, 256, 0, stream>>>(x, w_qkv, w_proj, xb, wqkvt, wprojt);
    gemm_qkv<<<dim3(18, 32), 256, 0, stream>>>(xb, wqkvt, b_qkv, qpack, kpack, vt);
    attn_fused<<<768, 256, 0, stream>>>(qpack, kpack, vt, attnb);
    gemm_bt<<<dim3(6, 64), 256, 0, stream>>>(attnb, wprojt, b_proj, out, 8192, 768, 768);
}